// Round 9
// baseline (298.541 us; speedup 1.0000x reference)
//
#include <hip/hip_runtime.h>
#include <stdint.h>

#define B_    4
#define QDIM  48
#define KDIM  160
#define HO    113            // KDIM - QDIM + 1
#define NQ    (QDIM*QDIM)    // 2304
#define NB    (KDIM*QDIM)    // 7680
#define NR    (NB+NQ)        // 9984 real entries
#define T_    1024           // 16 waves
#define NW    16
#define NP    10             // entries/thread (padded to NPAD)
#define NPAD  10240          // 1024*10
#define NCH   10             // chunks of 1024 entries
#define NPAIR 57             // ceil(113/2)

// swizzle for u16 count array: stride-17 in the blocked scan, 2-way max in count
#define CIDX16(f) ((f) + ((f) >> 4))

__device__ __forceinline__ uint32_t f2s(float v) {
  uint32_t u = __float_as_uint(v);
  return u ^ ((u & 0x80000000u) ? 0xFFFFFFFFu : 0x80000000u);
}
__device__ __forceinline__ float s2f(uint32_t s) {
  return __uint_as_float(s ^ ((s & 0x80000000u) ? 0x80000000u : 0xFFFFFFFFu));
}

// canonical gfx9/CDNA wave64 inclusive scan: 6 VALU adds via DPP (no LDS ops)
__device__ __forceinline__ int dpp_scan_incl(int v) {
  v += __builtin_amdgcn_update_dpp(0, v, 0x111, 0xF, 0xF, false); // row_shr:1
  v += __builtin_amdgcn_update_dpp(0, v, 0x112, 0xF, 0xF, false); // row_shr:2
  v += __builtin_amdgcn_update_dpp(0, v, 0x114, 0xF, 0xF, false); // row_shr:4
  v += __builtin_amdgcn_update_dpp(0, v, 0x118, 0xF, 0xF, false); // row_shr:8
  v += __builtin_amdgcn_update_dpp(0, v, 0x142, 0xA, 0xF, false); // row_bcast:15 -> rows 1,3
  v += __builtin_amdgcn_update_dpp(0, v, 0x143, 0xC, 0xF, false); // row_bcast:31 -> rows 2,3
  return v;
}

__global__ void ps_init(unsigned long long* slots) {
  if (threadIdx.x < B_) slots[threadIdx.x] = ~0ULL;
}

__global__ __launch_bounds__(T_, 4)
void ps_band_kernel(const float* __restrict__ query,
                    const float* __restrict__ key,
                    unsigned long long* __restrict__ slots) {
  // E (80KB) doubles as kA|kB during the sort (exactly 2*NPAD u32)
  __shared__ unsigned long long E[NPAD];
  __shared__ uint8_t  pA[NPAD];
  __shared__ uint8_t  pB[NPAD];
  alignas(16) __shared__ uint16_t cnt[17408];
  __shared__ int      waveTot[NW], waveBase[NW];
  __shared__ unsigned long long wbest[NW];

  uint32_t* kA = (uint32_t*)E;
  uint32_t* kB = kA + NPAD;

  const int t    = threadIdx.x;
  const int lane = t & 63;
  const int w    = t >> 6;
  const int b    = blockIdx.x / HO;
  const int oy   = blockIdx.x % HO;
  const float* kp = key   + b * KDIM * KDIM;
  const float* qp = query + b * NQ;

  // ---- load band + query (+pad) ----
  for (int i = t; i < NPAD; i += T_) {
    uint32_t kk, pp;
    if (i < NB) {
      int r = i / KDIM; int x = i - r * KDIM;
      kk = f2s(kp[(oy + r) * KDIM + x]); pp = (uint32_t)x;
    } else if (i < NR) {
      kk = f2s(qp[i - NB]); pp = 255u;        // query sentinel (d=-1)
    } else {
      kk = 0xFFFFFFFFu; pp = 254u;            // pad sentinel (d=0, gap=0)
    }
    kA[i] = kk; pA[i] = (uint8_t)pp;
  }
  __syncthreads();

  const int base = t * NP;                    // even -> uint2-aligned

  // ---- 8-pass 4-bit LSD radix sort, register-staged, u16 counts ----
  for (int p = 0; p < 8; ++p) {
    uint32_t* sK = (p & 1) ? kB : kA;
    uint32_t* dK = (p & 1) ? kA : kB;
    uint8_t*  sP = (p & 1) ? pB : pA;
    uint8_t*  dP = (p & 1) ? pA : pB;
    const int sh = p * 4;

    for (int i = t; i < 2176; i += T_) ((uint4*)cnt)[i] = make_uint4(0,0,0,0);
    __syncthreads();

    uint32_t kreg[NP]; uint32_t preg[NP];
    {
      const uint2* kv = reinterpret_cast<const uint2*>(sK + base);
      #pragma unroll
      for (int j = 0; j < 5; ++j) { uint2 q = kv[j]; kreg[2*j] = q.x; kreg[2*j+1] = q.y; }
      const uint16_t* pv = reinterpret_cast<const uint16_t*>(sP + base); // byte off t*10, 2-aligned
      #pragma unroll
      for (int j = 0; j < 5; ++j) { uint32_t q = pv[j]; preg[2*j] = q & 0xFFu; preg[2*j+1] = q >> 8; }
    }

    #pragma unroll
    for (int j = 0; j < NP; ++j) {
      uint32_t f = CIDX16(((kreg[j] >> sh) & 15u) * T_ + t);
      cnt[f] = (uint16_t)(cnt[f] + 1);
    }
    __syncthreads();

    // blocked flat scan: 16 slots/thread in regs (stride-17 u16 addresses)
    uint32_t cex[16]; int s = 0;
    #pragma unroll
    for (int j = 0; j < 16; ++j) { int c = cnt[CIDX16(16 * t + j)]; cex[j] = (uint32_t)s; s += c; }

    int incl = dpp_scan_incl(s);
    if (lane == 63) waveTot[w] = incl;
    const int wexcl = incl - s;
    __syncthreads();
    if (t < NW) {
      int v = waveTot[t]; int iw = v;
      #pragma unroll
      for (int d = 1; d < NW; d <<= 1) { int o = __shfl_up(iw, d, NW); if (t >= d) iw += o; }
      waveBase[t] = iw - v;
    }
    __syncthreads();
    const int tb = waveBase[w] + wexcl;
    #pragma unroll
    for (int j = 0; j < 16; ++j) cnt[CIDX16(16 * t + j)] = (uint16_t)(cex[j] + (uint32_t)tb);
    __syncthreads();

    // stable scatter
    #pragma unroll
    for (int j = 0; j < NP; ++j) {
      uint32_t f = CIDX16(((kreg[j] >> sh) & 15u) * T_ + t);
      uint32_t pos = cnt[f];
      cnt[f] = (uint16_t)(pos + 1);
      dK[pos] = kreg[j];
      dP[pos] = (uint8_t)preg[j];
    }
    __syncthreads();
  }
  // sorted: keys in kA, payload in pA

  // ---- build packed (gap,x) stream E in bank-transposed layout ----
  // logical entry i: chunk c=i>>10, l=(i>>4)&63, sub=(i>>1)&7, q=i&1
  // phys u64 idx = c*1024 + sub*128 + l*2 + q
  {
    uint32_t kk2[NP + 1]; uint32_t pp2[NP];
    {
      const uint2* k2 = reinterpret_cast<const uint2*>(kA + base);
      #pragma unroll
      for (int j = 0; j < 5; ++j) { uint2 q = k2[j]; kk2[2*j] = q.x; kk2[2*j+1] = q.y; }
      kk2[NP] = (t == T_ - 1) ? 0xFFFFFFFFu : kA[base + NP];
      const uint16_t* p2 = reinterpret_cast<const uint16_t*>(pA + base);
      #pragma unroll
      for (int j = 0; j < 5; ++j) { uint32_t q = p2[j]; pp2[2*j] = q & 0xFFu; pp2[2*j+1] = q >> 8; }
    }
    __syncthreads();   // everyone staged before E overwrites kA/kB
    #pragma unroll
    for (int j = 0; j < NP; j += 2) {
      int i = base + j;
      float g0 = (i     < NR - 1) ? s2f(kk2[j + 1]) - s2f(kk2[j])     : 0.0f;
      float g1 = (i + 1 < NR - 1) ? s2f(kk2[j + 2]) - s2f(kk2[j + 1]) : 0.0f;
      int c = i >> 10, e = i & 1023;
      int l = e >> 4, sb = (e >> 1) & 7;
      int pidx = c * 1024 + sb * 128 + l * 2;
      E[pidx]     = (unsigned long long)__float_as_uint(g0) | ((unsigned long long)pp2[j]     << 32);
      E[pidx + 1] = (unsigned long long)__float_as_uint(g1) | ((unsigned long long)pp2[j + 1] << 32);
    }
    __syncthreads();
  }

  // ---- eval: one ox-PAIR per wave, zero block barriers, DPP scans ----
  unsigned long long mybest = ~0ULL;
  for (int pr = w; pr < NPAIR; pr += NW) {
    const int oxa = 2 * pr, oxb = 2 * pr + 1;   // oxb==113 invalid at pr==56
    int carry_a = 0, carry_b = 0;
    float acc_a = 0.f, acc_b = 0.f;
    for (int c = 0; c < NCH; ++c) {
      float ga[16]; int pa_[16], pb_[16];
      int ra = 0, rb = 0;
      const uint4* Ep4 = reinterpret_cast<const uint4*>(E + (c * 1024 + lane * 2));
      #pragma unroll
      for (int sb = 0; sb < 8; ++sb) {
        uint4 e = Ep4[sb * 64];   // two u64 entries: (e.x=g0,e.y=x0),(e.z=g1,e.w=x1)
        {
          uint32_t x = e.y;
          int dq = (x == 255u) ? -1 : 0;
          ra += ((x - (uint32_t)oxa) < (uint32_t)QDIM) ? 1 : dq;
          rb += ((x - (uint32_t)oxb) < (uint32_t)QDIM) ? 1 : dq;
          ga[2 * sb] = __uint_as_float(e.x); pa_[2 * sb] = ra; pb_[2 * sb] = rb;
        }
        {
          uint32_t x = e.w;
          int dq = (x == 255u) ? -1 : 0;
          ra += ((x - (uint32_t)oxa) < (uint32_t)QDIM) ? 1 : dq;
          rb += ((x - (uint32_t)oxb) < (uint32_t)QDIM) ? 1 : dq;
          ga[2 * sb + 1] = __uint_as_float(e.z); pa_[2 * sb + 1] = ra; pb_[2 * sb + 1] = rb;
        }
      }
      const int ia = dpp_scan_incl(ra);
      const int ib = dpp_scan_incl(rb);
      const int base_a = carry_a + (ia - ra);
      const int base_b = carry_b + (ib - rb);
      carry_a += __builtin_amdgcn_readlane(ia, 63);
      carry_b += __builtin_amdgcn_readlane(ib, 63);
      #pragma unroll
      for (int j = 0; j < 16; ++j) {
        acc_a = fmaf(fabsf((float)(base_a + pa_[j])), ga[j], acc_a);
        acc_b = fmaf(fabsf((float)(base_b + pb_[j])), ga[j], acc_b);
      }
    }
    // wave total
    #pragma unroll
    for (int d = 32; d >= 1; d >>= 1) {
      acc_a += __shfl_xor(acc_a, d, 64);
      acc_b += __shfl_xor(acc_b, d, 64);
    }
    if (lane == 0) {
      unsigned long long ca =
        (((unsigned long long)__float_as_uint(acc_a)) << 32) | (unsigned)(oy * HO + oxa);
      if (ca < mybest) mybest = ca;
      if (oxb < HO) {
        unsigned long long cb =
          (((unsigned long long)__float_as_uint(acc_b)) << 32) | (unsigned)(oy * HO + oxb);
        if (cb < mybest) mybest = cb;
      }
    }
  }

  if (lane == 0) wbest[w] = mybest;
  __syncthreads();
  if (t == 0) {
    unsigned long long m = wbest[0];
    #pragma unroll
    for (int i = 1; i < NW; ++i) m = (wbest[i] < m) ? wbest[i] : m;
    atomicMin(slots + b, m);
  }
}

__global__ void ps_final(const unsigned long long* __restrict__ slots,
                         int* __restrict__ out) {
  int t = threadIdx.x;
  if (t < B_) out[t] = (int)(unsigned)(slots[t] & 0xFFFFFFFFull);
  if (t == B_) out[t] = HO;
}

extern "C" void kernel_launch(void* const* d_in, const int* in_sizes, int n_in,
                              void* d_out, int out_size, void* d_ws, size_t ws_size,
                              hipStream_t stream) {
  const float* query = (const float*)d_in[0];   // [4,1,48,48]
  const float* key   = (const float*)d_in[1];   // [4,1,160,160]
  unsigned long long* slots = (unsigned long long*)d_ws;
  int* out = (int*)d_out;

  hipLaunchKernelGGL(ps_init, dim3(1), dim3(64), 0, stream, slots);
  hipLaunchKernelGGL(ps_band_kernel, dim3(B_ * HO), dim3(T_), 0, stream,
                     query, key, slots);
  hipLaunchKernelGGL(ps_final, dim3(1), dim3(64), 0, stream, slots, out);
}

// Round 10
// 270.491 us; speedup vs baseline: 1.1037x; 1.1037x over previous
//
#include <hip/hip_runtime.h>
#include <stdint.h>

#define B_    4
#define QDIM  48
#define KDIM  160
#define HO    113            // KDIM - QDIM + 1
#define NQ    (QDIM*QDIM)    // 2304
#define NB    (KDIM*QDIM)    // 7680 (fused path)
#define NR    (NB+NQ)        // 9984 (fused path)
#define NGRP  57             // oy-pair groups per batch (last group single oy)
#define GROWS 49
#define NB2   (GROWS*KDIM)   // 7840
#define NE2   (NB2+NQ)       // 10144 real entries in group array
#define T_    1024           // 16 waves
#define NW    16
#define NP    10             // entries/thread
#define NPAD  10240          // 1024*10
#define NCH   10             // chunks of 1024 entries
#define NPAIR 57             // ceil(113/2) ox-pairs

#define CIDX16(f) ((f) + ((f) >> 4))

__device__ __forceinline__ uint32_t f2s(float v) {
  uint32_t u = __float_as_uint(v);
  return u ^ ((u & 0x80000000u) ? 0xFFFFFFFFu : 0x80000000u);
}
__device__ __forceinline__ float s2f(uint32_t s) {
  return __uint_as_float(s ^ ((s & 0x80000000u) ? 0x80000000u : 0xFFFFFFFFu));
}

// wave64 inclusive scan: 6 VALU adds via DPP
__device__ __forceinline__ int dpp_scan_incl(int v) {
  v += __builtin_amdgcn_update_dpp(0, v, 0x111, 0xF, 0xF, false); // row_shr:1
  v += __builtin_amdgcn_update_dpp(0, v, 0x112, 0xF, 0xF, false); // row_shr:2
  v += __builtin_amdgcn_update_dpp(0, v, 0x114, 0xF, 0xF, false); // row_shr:4
  v += __builtin_amdgcn_update_dpp(0, v, 0x118, 0xF, 0xF, false); // row_shr:8
  v += __builtin_amdgcn_update_dpp(0, v, 0x142, 0xA, 0xF, false); // row_bcast:15
  v += __builtin_amdgcn_update_dpp(0, v, 0x143, 0xC, 0xF, false); // row_bcast:31
  return v;
}

__global__ void ps_init(unsigned long long* slots) {
  if (threadIdx.x < B_) slots[threadIdx.x] = ~0ULL;
}

// ================= split path: sort kernel (one block per oy-PAIR) ==========
__global__ __launch_bounds__(T_, 4)
void ps_sort_kernel(const float* __restrict__ query,
                    const float* __restrict__ key,
                    unsigned long long* __restrict__ Ebase) {
  __shared__ uint32_t kA[NPAD];
  __shared__ uint32_t kB[NPAD];
  __shared__ uint16_t pA[NPAD];
  __shared__ uint16_t pB[NPAD];
  alignas(16) __shared__ uint16_t cnt[17408];
  __shared__ int waveTot[NW], waveBase[NW];

  const int t    = threadIdx.x;
  const int lane = t & 63;
  const int w    = t >> 6;
  const int b    = blockIdx.x / NGRP;
  const int g    = blockIdx.x % NGRP;
  const int oy0  = 2 * g;
  const float* kp = key   + b * KDIM * KDIM;
  const float* qp = query + b * NQ;

  // ---- load 49-row band + query (+pad); payload u16: x | r<<8 | isQ<<15 ----
  for (int i = t; i < NPAD; i += T_) {
    uint32_t kk, pp;
    if (i < NB2) {
      int r = i / KDIM, x = i - r * KDIM;
      int row = oy0 + r;
      if (row < KDIM) { kk = f2s(kp[row * KDIM + x]); pp = (uint32_t)x | ((uint32_t)r << 8); }
      else            { kk = 0xFFFFFFFFu; pp = 254u | (63u << 8); }   // nonexistent row -> pad
    } else if (i < NE2) {
      kk = f2s(qp[i - NB2]); pp = 255u | (63u << 8) | 0x8000u;        // query
    } else {
      kk = 0xFFFFFFFFu; pp = 254u | (63u << 8);                       // tail pad
    }
    kA[i] = kk; pA[i] = (uint16_t)pp;
  }
  __syncthreads();

  const int base = t * NP;

  // ---- 8-pass 4-bit LSD radix sort, register-staged, u16 counts/payloads ----
  for (int p = 0; p < 8; ++p) {
    uint32_t* sK = (p & 1) ? kB : kA;
    uint32_t* dK = (p & 1) ? kA : kB;
    uint16_t* sP = (p & 1) ? pB : pA;
    uint16_t* dP = (p & 1) ? pA : pB;
    const int sh = p * 4;

    for (int i = t; i < 2176; i += T_) ((uint4*)cnt)[i] = make_uint4(0,0,0,0);
    __syncthreads();

    uint32_t kreg[NP]; uint32_t preg[NP];
    {
      const uint2* kv = reinterpret_cast<const uint2*>(sK + base);
      #pragma unroll
      for (int j = 0; j < 5; ++j) { uint2 q = kv[j]; kreg[2*j] = q.x; kreg[2*j+1] = q.y; }
      const uint32_t* pv = reinterpret_cast<const uint32_t*>(sP + base); // byte off t*20, 4-aligned
      #pragma unroll
      for (int j = 0; j < 5; ++j) { uint32_t q = pv[j]; preg[2*j] = q & 0xFFFFu; preg[2*j+1] = q >> 16; }
    }

    #pragma unroll
    for (int j = 0; j < NP; ++j) {
      uint32_t f = CIDX16(((kreg[j] >> sh) & 15u) * T_ + t);
      cnt[f] = (uint16_t)(cnt[f] + 1);
    }
    __syncthreads();

    uint32_t cex[16]; int s = 0;
    #pragma unroll
    for (int j = 0; j < 16; ++j) { int c = cnt[CIDX16(16 * t + j)]; cex[j] = (uint32_t)s; s += c; }

    int incl = dpp_scan_incl(s);
    if (lane == 63) waveTot[w] = incl;
    const int wexcl = incl - s;
    __syncthreads();
    if (t < NW) {
      int v = waveTot[t]; int iw = v;
      #pragma unroll
      for (int d = 1; d < NW; d <<= 1) { int o = __shfl_up(iw, d, NW); if (t >= d) iw += o; }
      waveBase[t] = iw - v;
    }
    __syncthreads();
    const int tb = waveBase[w] + wexcl;
    #pragma unroll
    for (int j = 0; j < 16; ++j) cnt[CIDX16(16 * t + j)] = (uint16_t)(cex[j] + (uint32_t)tb);
    __syncthreads();

    #pragma unroll
    for (int j = 0; j < NP; ++j) {
      uint32_t f = CIDX16(((kreg[j] >> sh) & 15u) * T_ + t);
      uint32_t pos = cnt[f];
      cnt[f] = (uint16_t)(pos + 1);
      dK[pos] = kreg[j];
      dP[pos] = (uint16_t)preg[j];
    }
    __syncthreads();
  }
  // sorted: keys in kA, payload in pA

  // ---- emit TWO pre-masked E streams (transposed layout) to global ws ----
  // sel=0: active rows r in [0,47]; sel=1: r in [1,48]; query->255, inactive->254
  {
    uint32_t kk2[NP + 1]; uint32_t pp2[NP];
    {
      const uint2* k2 = reinterpret_cast<const uint2*>(kA + base);
      #pragma unroll
      for (int j = 0; j < 5; ++j) { uint2 q = k2[j]; kk2[2*j] = q.x; kk2[2*j+1] = q.y; }
      kk2[NP] = (t == T_ - 1) ? 0xFFFFFFFFu : kA[base + NP];
      const uint32_t* p2 = reinterpret_cast<const uint32_t*>(pA + base);
      #pragma unroll
      for (int j = 0; j < 5; ++j) { uint32_t q = p2[j]; pp2[2*j] = q & 0xFFFFu; pp2[2*j+1] = q >> 16; }
    }
    unsigned long long* E0 = Ebase + (size_t)(b * NGRP + g) * 2u * NPAD;
    unsigned long long* E1 = E0 + NPAD;
    #pragma unroll
    for (int j = 0; j < NP; j += 2) {
      int i = base + j;
      // gap=0 when next key is the pad sentinel (covers last-real and tail)
      float g0 = (kk2[j + 1] != 0xFFFFFFFFu) ? s2f(kk2[j + 1]) - s2f(kk2[j])     : 0.0f;
      float g1 = (kk2[j + 2] != 0xFFFFFFFFu) ? s2f(kk2[j + 2]) - s2f(kk2[j + 1]) : 0.0f;
      uint32_t x0 = pp2[j] & 255u,   r0 = (pp2[j] >> 8) & 63u,   q0 = pp2[j] >> 15;
      uint32_t x1 = pp2[j+1] & 255u, r1 = (pp2[j+1] >> 8) & 63u, q1 = pp2[j+1] >> 15;
      uint32_t a00 = q0 ? 255u : ((r0 < 48u) ? x0 : 254u);
      uint32_t a01 = q0 ? 255u : (((r0 - 1u) < 48u) ? x0 : 254u);
      uint32_t a10 = q1 ? 255u : ((r1 < 48u) ? x1 : 254u);
      uint32_t a11 = q1 ? 255u : (((r1 - 1u) < 48u) ? x1 : 254u);
      int c = i >> 10, e = i & 1023;
      int l = e >> 4, sb = (e >> 1) & 7;
      int pidx = c * 1024 + sb * 128 + l * 2;
      ulonglong2 v0, v1;
      v0.x = (unsigned long long)__float_as_uint(g0) | ((unsigned long long)a00 << 32);
      v0.y = (unsigned long long)__float_as_uint(g1) | ((unsigned long long)a10 << 32);
      v1.x = (unsigned long long)__float_as_uint(g0) | ((unsigned long long)a01 << 32);
      v1.y = (unsigned long long)__float_as_uint(g1) | ((unsigned long long)a11 << 32);
      *reinterpret_cast<ulonglong2*>(E0 + pidx) = v0;
      *reinterpret_cast<ulonglong2*>(E1 + pidx) = v1;
    }
  }
}

// ================= split path: eval kernel (one block per oy) ===============
__global__ __launch_bounds__(T_, 4)
void ps_eval_kernel(const unsigned long long* __restrict__ Ebase,
                    unsigned long long* __restrict__ slots) {
  __shared__ uint4 E4[NPAD / 2];           // 80 KB, transposed layout
  __shared__ unsigned long long wbest[NW];

  const int t    = threadIdx.x;
  const int lane = t & 63;
  const int w    = t >> 6;
  const int b    = blockIdx.x / HO;
  const int oy   = blockIdx.x % HO;
  const int g    = oy >> 1, sel = oy & 1;

  const uint4* src = reinterpret_cast<const uint4*>(
      Ebase + ((size_t)(b * NGRP + g) * 2u + (unsigned)sel) * NPAD);
  for (int i = t; i < NPAD / 2; i += T_) E4[i] = src[i];
  __syncthreads();

  unsigned long long mybest = ~0ULL;
  for (int pr = w; pr < NPAIR; pr += NW) {
    const int oxa = 2 * pr, oxb = 2 * pr + 1;
    int carry_a = 0, carry_b = 0;
    float acc_a = 0.f, acc_b = 0.f;
    for (int c = 0; c < NCH; ++c) {
      float ga[16]; int pa_[16], pb_[16];
      int ra = 0, rb = 0;
      const uint4* Ep4 = &E4[c * 512 + lane];
      #pragma unroll
      for (int sb = 0; sb < 8; ++sb) {
        uint4 e = Ep4[sb * 64];
        {
          uint32_t x = e.y;
          int dq = (x == 255u) ? -1 : 0;
          ra += ((x - (uint32_t)oxa) < (uint32_t)QDIM) ? 1 : dq;
          rb += ((x - (uint32_t)oxb) < (uint32_t)QDIM) ? 1 : dq;
          ga[2 * sb] = __uint_as_float(e.x); pa_[2 * sb] = ra; pb_[2 * sb] = rb;
        }
        {
          uint32_t x = e.w;
          int dq = (x == 255u) ? -1 : 0;
          ra += ((x - (uint32_t)oxa) < (uint32_t)QDIM) ? 1 : dq;
          rb += ((x - (uint32_t)oxb) < (uint32_t)QDIM) ? 1 : dq;
          ga[2 * sb + 1] = __uint_as_float(e.z); pa_[2 * sb + 1] = ra; pb_[2 * sb + 1] = rb;
        }
      }
      const int ia = dpp_scan_incl(ra);
      const int ib = dpp_scan_incl(rb);
      const int base_a = carry_a + (ia - ra);
      const int base_b = carry_b + (ib - rb);
      carry_a += __builtin_amdgcn_readlane(ia, 63);
      carry_b += __builtin_amdgcn_readlane(ib, 63);
      #pragma unroll
      for (int j = 0; j < 16; ++j) {
        acc_a = fmaf(fabsf((float)(base_a + pa_[j])), ga[j], acc_a);
        acc_b = fmaf(fabsf((float)(base_b + pb_[j])), ga[j], acc_b);
      }
    }
    #pragma unroll
    for (int d = 32; d >= 1; d >>= 1) {
      acc_a += __shfl_xor(acc_a, d, 64);
      acc_b += __shfl_xor(acc_b, d, 64);
    }
    if (lane == 0) {
      unsigned long long ca =
        (((unsigned long long)__float_as_uint(acc_a)) << 32) | (unsigned)(oy * HO + oxa);
      if (ca < mybest) mybest = ca;
      if (oxb < HO) {
        unsigned long long cb =
          (((unsigned long long)__float_as_uint(acc_b)) << 32) | (unsigned)(oy * HO + oxb);
        if (cb < mybest) mybest = cb;
      }
    }
  }

  if (lane == 0) wbest[w] = mybest;
  __syncthreads();
  if (t == 0) {
    unsigned long long m = wbest[0];
    #pragma unroll
    for (int i = 1; i < NW; ++i) m = (wbest[i] < m) ? wbest[i] : m;
    atomicMin(slots + b, m);
  }
}

// ================= fallback: round-9 fused kernel (measured 256us) ==========
__global__ __launch_bounds__(T_, 4)
void ps_band_fused(const float* __restrict__ query,
                   const float* __restrict__ key,
                   unsigned long long* __restrict__ slots) {
  __shared__ unsigned long long E[NPAD];
  __shared__ uint8_t  pA[NPAD];
  __shared__ uint8_t  pB[NPAD];
  alignas(16) __shared__ uint16_t cnt[17408];
  __shared__ int      waveTot[NW], waveBase[NW];
  __shared__ unsigned long long wbest[NW];

  uint32_t* kA = (uint32_t*)E;
  uint32_t* kB = kA + NPAD;

  const int t    = threadIdx.x;
  const int lane = t & 63;
  const int w    = t >> 6;
  const int b    = blockIdx.x / HO;
  const int oy   = blockIdx.x % HO;
  const float* kp = key   + b * KDIM * KDIM;
  const float* qp = query + b * NQ;

  for (int i = t; i < NPAD; i += T_) {
    uint32_t kk, pp;
    if (i < NB) {
      int r = i / KDIM; int x = i - r * KDIM;
      kk = f2s(kp[(oy + r) * KDIM + x]); pp = (uint32_t)x;
    } else if (i < NR) {
      kk = f2s(qp[i - NB]); pp = 255u;
    } else {
      kk = 0xFFFFFFFFu; pp = 254u;
    }
    kA[i] = kk; pA[i] = (uint8_t)pp;
  }
  __syncthreads();

  const int base = t * NP;

  for (int p = 0; p < 8; ++p) {
    uint32_t* sK = (p & 1) ? kB : kA;
    uint32_t* dK = (p & 1) ? kA : kB;
    uint8_t*  sP = (p & 1) ? pB : pA;
    uint8_t*  dP = (p & 1) ? pA : pB;
    const int sh = p * 4;

    for (int i = t; i < 2176; i += T_) ((uint4*)cnt)[i] = make_uint4(0,0,0,0);
    __syncthreads();

    uint32_t kreg[NP]; uint32_t preg[NP];
    {
      const uint2* kv = reinterpret_cast<const uint2*>(sK + base);
      #pragma unroll
      for (int j = 0; j < 5; ++j) { uint2 q = kv[j]; kreg[2*j] = q.x; kreg[2*j+1] = q.y; }
      const uint16_t* pv = reinterpret_cast<const uint16_t*>(sP + base);
      #pragma unroll
      for (int j = 0; j < 5; ++j) { uint32_t q = pv[j]; preg[2*j] = q & 0xFFu; preg[2*j+1] = q >> 8; }
    }

    #pragma unroll
    for (int j = 0; j < NP; ++j) {
      uint32_t f = CIDX16(((kreg[j] >> sh) & 15u) * T_ + t);
      cnt[f] = (uint16_t)(cnt[f] + 1);
    }
    __syncthreads();

    uint32_t cex[16]; int s = 0;
    #pragma unroll
    for (int j = 0; j < 16; ++j) { int c = cnt[CIDX16(16 * t + j)]; cex[j] = (uint32_t)s; s += c; }

    int incl = dpp_scan_incl(s);
    if (lane == 63) waveTot[w] = incl;
    const int wexcl = incl - s;
    __syncthreads();
    if (t < NW) {
      int v = waveTot[t]; int iw = v;
      #pragma unroll
      for (int d = 1; d < NW; d <<= 1) { int o = __shfl_up(iw, d, NW); if (t >= d) iw += o; }
      waveBase[t] = iw - v;
    }
    __syncthreads();
    const int tb = waveBase[w] + wexcl;
    #pragma unroll
    for (int j = 0; j < 16; ++j) cnt[CIDX16(16 * t + j)] = (uint16_t)(cex[j] + (uint32_t)tb);
    __syncthreads();

    #pragma unroll
    for (int j = 0; j < NP; ++j) {
      uint32_t f = CIDX16(((kreg[j] >> sh) & 15u) * T_ + t);
      uint32_t pos = cnt[f];
      cnt[f] = (uint16_t)(pos + 1);
      dK[pos] = kreg[j];
      dP[pos] = (uint8_t)preg[j];
    }
    __syncthreads();
  }

  {
    uint32_t kk2[NP + 1]; uint32_t pp2[NP];
    {
      const uint2* k2 = reinterpret_cast<const uint2*>(kA + base);
      #pragma unroll
      for (int j = 0; j < 5; ++j) { uint2 q = k2[j]; kk2[2*j] = q.x; kk2[2*j+1] = q.y; }
      kk2[NP] = (t == T_ - 1) ? 0xFFFFFFFFu : kA[base + NP];
      const uint16_t* p2 = reinterpret_cast<const uint16_t*>(pA + base);
      #pragma unroll
      for (int j = 0; j < 5; ++j) { uint32_t q = p2[j]; pp2[2*j] = q & 0xFFu; pp2[2*j+1] = q >> 8; }
    }
    __syncthreads();
    #pragma unroll
    for (int j = 0; j < NP; j += 2) {
      int i = base + j;
      float g0 = (i     < NR - 1) ? s2f(kk2[j + 1]) - s2f(kk2[j])     : 0.0f;
      float g1 = (i + 1 < NR - 1) ? s2f(kk2[j + 2]) - s2f(kk2[j + 1]) : 0.0f;
      int c = i >> 10, e = i & 1023;
      int l = e >> 4, sb = (e >> 1) & 7;
      int pidx = c * 1024 + sb * 128 + l * 2;
      E[pidx]     = (unsigned long long)__float_as_uint(g0) | ((unsigned long long)pp2[j]     << 32);
      E[pidx + 1] = (unsigned long long)__float_as_uint(g1) | ((unsigned long long)pp2[j + 1] << 32);
    }
    __syncthreads();
  }

  unsigned long long mybest = ~0ULL;
  for (int pr = w; pr < NPAIR; pr += NW) {
    const int oxa = 2 * pr, oxb = 2 * pr + 1;
    int carry_a = 0, carry_b = 0;
    float acc_a = 0.f, acc_b = 0.f;
    for (int c = 0; c < NCH; ++c) {
      float ga[16]; int pa_[16], pb_[16];
      int ra = 0, rb = 0;
      const uint4* Ep4 = reinterpret_cast<const uint4*>(E + (c * 1024 + lane * 2));
      #pragma unroll
      for (int sb = 0; sb < 8; ++sb) {
        uint4 e = Ep4[sb * 64];
        {
          uint32_t x = e.y;
          int dq = (x == 255u) ? -1 : 0;
          ra += ((x - (uint32_t)oxa) < (uint32_t)QDIM) ? 1 : dq;
          rb += ((x - (uint32_t)oxb) < (uint32_t)QDIM) ? 1 : dq;
          ga[2 * sb] = __uint_as_float(e.x); pa_[2 * sb] = ra; pb_[2 * sb] = rb;
        }
        {
          uint32_t x = e.w;
          int dq = (x == 255u) ? -1 : 0;
          ra += ((x - (uint32_t)oxa) < (uint32_t)QDIM) ? 1 : dq;
          rb += ((x - (uint32_t)oxb) < (uint32_t)QDIM) ? 1 : dq;
          ga[2 * sb + 1] = __uint_as_float(e.z); pa_[2 * sb + 1] = ra; pb_[2 * sb + 1] = rb;
        }
      }
      const int ia = dpp_scan_incl(ra);
      const int ib = dpp_scan_incl(rb);
      const int base_a = carry_a + (ia - ra);
      const int base_b = carry_b + (ib - rb);
      carry_a += __builtin_amdgcn_readlane(ia, 63);
      carry_b += __builtin_amdgcn_readlane(ib, 63);
      #pragma unroll
      for (int j = 0; j < 16; ++j) {
        acc_a = fmaf(fabsf((float)(base_a + pa_[j])), ga[j], acc_a);
        acc_b = fmaf(fabsf((float)(base_b + pb_[j])), ga[j], acc_b);
      }
    }
    #pragma unroll
    for (int d = 32; d >= 1; d >>= 1) {
      acc_a += __shfl_xor(acc_a, d, 64);
      acc_b += __shfl_xor(acc_b, d, 64);
    }
    if (lane == 0) {
      unsigned long long ca =
        (((unsigned long long)__float_as_uint(acc_a)) << 32) | (unsigned)(oy * HO + oxa);
      if (ca < mybest) mybest = ca;
      if (oxb < HO) {
        unsigned long long cb =
          (((unsigned long long)__float_as_uint(acc_b)) << 32) | (unsigned)(oy * HO + oxb);
        if (cb < mybest) mybest = cb;
      }
    }
  }

  if (lane == 0) wbest[w] = mybest;
  __syncthreads();
  if (t == 0) {
    unsigned long long m = wbest[0];
    #pragma unroll
    for (int i = 1; i < NW; ++i) m = (wbest[i] < m) ? wbest[i] : m;
    atomicMin(slots + b, m);
  }
}

__global__ void ps_final(const unsigned long long* __restrict__ slots,
                         int* __restrict__ out) {
  int t = threadIdx.x;
  if (t < B_) out[t] = (int)(unsigned)(slots[t] & 0xFFFFFFFFull);
  if (t == B_) out[t] = HO;
}

extern "C" void kernel_launch(void* const* d_in, const int* in_sizes, int n_in,
                              void* d_out, int out_size, void* d_ws, size_t ws_size,
                              hipStream_t stream) {
  const float* query = (const float*)d_in[0];   // [4,1,48,48]
  const float* key   = (const float*)d_in[1];   // [4,1,160,160]
  unsigned long long* slots = (unsigned long long*)d_ws;
  int* out = (int*)d_out;

  const size_t need = 256 + (size_t)B_ * NGRP * 2u * NPAD * 8u;  // ~37.4 MB

  hipLaunchKernelGGL(ps_init, dim3(1), dim3(64), 0, stream, slots);
  if (ws_size >= need) {
    unsigned long long* Ebase = (unsigned long long*)((char*)d_ws + 256);
    hipLaunchKernelGGL(ps_sort_kernel, dim3(B_ * NGRP), dim3(T_), 0, stream,
                       query, key, Ebase);
    hipLaunchKernelGGL(ps_eval_kernel, dim3(B_ * HO), dim3(T_), 0, stream,
                       Ebase, slots);
  } else {
    hipLaunchKernelGGL(ps_band_fused, dim3(B_ * HO), dim3(T_), 0, stream,
                       query, key, slots);
  }
  hipLaunchKernelGGL(ps_final, dim3(1), dim3(64), 0, stream, slots, out);
}